// Round 1
// baseline (279.210 us; speedup 1.0000x reference)
//
#include <hip/hip_runtime.h>
#include <hip/hip_bf16.h>
#include <cstdint>

#define NBATCH 2
#define NSEQ   512
#define DHID   100

typedef __bf16 bf16x8 __attribute__((ext_vector_type(8)));
typedef float  f32x4  __attribute__((ext_vector_type(4)));

// ---------------- kernel 1: qk = x @ W_down + b_down (fp32, exact) ----------------
__global__ __launch_bounds__(128)
void proj_kernel(const float* __restrict__ x, const float* __restrict__ Wd,
                 const float* __restrict__ bd, float* __restrict__ qk)
{
    __shared__ float xs[512];
    const int row = blockIdx.x;      // 0..1023  (= b*512 + n)
    const int tid = threadIdx.x;     // 0..127   (= output column)
    const float* xr = x + row * 512;
    #pragma unroll
    for (int e = 0; e < 4; e++) xs[tid + 128 * e] = xr[tid + 128 * e];
    __syncthreads();
    float acc = bd[tid];
    #pragma unroll 8
    for (int e = 0; e < 512; e++)
        acc = fmaf(xs[e], Wd[e * 128 + tid], acc);
    qk[row * 128 + tid] = acc;
}

// ---------------- kernel 2: pairwise MLP ----------------
// Tile: 8 waves (512 thr). wave w -> i = i0 + w, TJ=32 j's (2 subtiles of 16 pairs).
// LDS: W1T swz [112][128]bf16 @0 (28672B), W2T swz @28672 (28672B),
//      hbuf per-wave [32][128]bf16 @57344 + w*8192 (65536B).  total 122880B.
// Swizzle: byte_in_row ^= (row&7)<<4   (16B granule XOR -> conflict-free b128 reads)

#define LDS_W2T  28672
#define LDS_H    57344
#define LDS_TOT  122880

__global__ __launch_bounds__(512, 2)
void pair_mlp_kernel(const float* __restrict__ qk,
                     const float* __restrict__ W1, const float* __restrict__ b1,
                     const float* __restrict__ W2, const float* __restrict__ b2,
                     float* __restrict__ dist, float* __restrict__ ang)
{
    extern __shared__ char smem[];
    const int tid  = threadIdx.x;
    const int w    = tid >> 6;        // wave 0..7
    const int lane = tid & 63;
    const int l16  = lane & 15;
    const int g    = lane >> 4;       // 0..3

    // ---- zero all LDS (guarantees zero-padding of h cols 100..127 and W pads) ----
    for (int idx = tid; idx < LDS_TOT / 4; idx += 512)
        ((float*)smem)[idx] = 0.f;
    __syncthreads();

    // ---- stage weights (once per block; bf16, swizzled, transposed) ----
    // W1T[n][k] = W1[k][n]   (n<100, k<128)
    for (int idx = tid; idx < 100 * 128; idx += 512) {
        int n = idx >> 7, k = idx & 127;
        int byte = n * 256 + ((2 * k) ^ ((n & 7) << 4));
        *(__bf16*)(smem + byte) = (__bf16)W1[k * DHID + n];
    }
    // W2T[n][k] = W2[k][n]   (n<100, k<100; k>=100 stays zero)
    for (int idx = tid; idx < 100 * 100; idx += 512) {
        int n = idx / 100, k = idx % 100;
        int byte = LDS_W2T + n * 256 + ((2 * k) ^ ((n & 7) << 4));
        *(__bf16*)(smem + byte) = (__bf16)W2[k * DHID + n];
    }
    __syncthreads();

    // ---- per-lane bias values (col = nt*16 + l16) ----
    float b1v[7], b2v[7];
    #pragma unroll
    for (int nt = 0; nt < 7; nt++) {
        int n = nt * 16 + l16;
        b1v[nt] = (n < DHID) ? b1[n] : 0.f;
        b2v[nt] = (n < DHID) ? b2[n] : 0.f;
    }

    char* hb = smem + LDS_H + w * 8192;
    const int TILES = NBATCH * (NSEQ / 8) * (NSEQ / 32);  // 2*64*16 = 2048

    for (int t = blockIdx.x; t < TILES; t += gridDim.x) {
        int tmp = t;
        const int jb = tmp & 15;  tmp >>= 4;
        const int ib = tmp & 63;  tmp >>= 6;
        const int bi = tmp;                    // batch
        const int i  = ib * 8 + w;
        const int j0 = jb * 32;

        // ---- q elements for this wave's i (shared across both subtiles) ----
        const float* qrow = qk + (size_t)(bi * NSEQ + i) * 128;
        f32x4 qa0 = *(const f32x4*)(qrow + g * 8);
        f32x4 qa1 = *(const f32x4*)(qrow + g * 8 + 4);
        f32x4 qb0 = *(const f32x4*)(qrow + 32 + g * 8);
        f32x4 qb1 = *(const f32x4*)(qrow + 32 + g * 8 + 4);

        // ---- build A fragments (pw) in registers: af[s][ks] ----
        // k index of frag elem j:  kk = ks*32 + g*8 + j
        // kk<64 : q[kk]*k[kk] ;  kk>=64 : k[kk-64]-q[kk-64]
        bf16x8 af[2][4];
        #pragma unroll
        for (int s = 0; s < 2; s++) {
            const float* krow = qk + (size_t)(bi * NSEQ + j0 + s * 16 + l16) * 128 + 64;
            f32x4 ka0 = *(const f32x4*)(krow + g * 8);
            f32x4 ka1 = *(const f32x4*)(krow + g * 8 + 4);
            f32x4 kb0 = *(const f32x4*)(krow + 32 + g * 8);
            f32x4 kb1 = *(const f32x4*)(krow + 32 + g * 8 + 4);
            #pragma unroll
            for (int j = 0; j < 4; j++) {
                af[s][0][j]     = (__bf16)(qa0[j] * ka0[j]);
                af[s][0][j + 4] = (__bf16)(qa1[j] * ka1[j]);
                af[s][1][j]     = (__bf16)(qb0[j] * kb0[j]);
                af[s][1][j + 4] = (__bf16)(qb1[j] * kb1[j]);
                af[s][2][j]     = (__bf16)(ka0[j] - qa0[j]);
                af[s][2][j + 4] = (__bf16)(ka1[j] - qa1[j]);
                af[s][3][j]     = (__bf16)(kb0[j] - qb0[j]);
                af[s][3][j + 4] = (__bf16)(kb1[j] - qb1[j]);
            }
        }

        // ---- GEMM1: h_pre = pw @ W1 + b1 ----
        f32x4 acc1[2][7];
        #pragma unroll
        for (int nt = 0; nt < 7; nt++) {
            f32x4 init = {b1v[nt], b1v[nt], b1v[nt], b1v[nt]};
            acc1[0][nt] = init; acc1[1][nt] = init;
        }
        #pragma unroll
        for (int nt = 0; nt < 7; nt++) {
            const int rbase = (nt * 16 + l16) * 256;
            const int sw    = ((nt * 16 + l16) & 7) << 4;
            #pragma unroll
            for (int ks = 0; ks < 4; ks++) {
                bf16x8 bf = *(const bf16x8*)(smem + rbase + ((64 * ks + 16 * g) ^ sw));
                acc1[0][nt] = __builtin_amdgcn_mfma_f32_16x16x32_bf16(af[0][ks], bf, acc1[0][nt], 0, 0, 0);
                acc1[1][nt] = __builtin_amdgcn_mfma_f32_16x16x32_bf16(af[1][ks], bf, acc1[1][nt], 0, 0, 0);
            }
        }

        // ---- silu -> bf16 -> wave-private LDS (transpose via LDS) ----
        #pragma unroll
        for (int s = 0; s < 2; s++)
            #pragma unroll
            for (int nt = 0; nt < 7; nt++)
                #pragma unroll
                for (int r = 0; r < 4; r++) {
                    float z  = acc1[s][nt][r];
                    float hv = z / (1.f + __expf(-z));
                    if (nt == 6 && l16 >= 4) hv = 0.f;   // cols 100..111 must be exact zero
                    int rr   = s * 16 + g * 4 + r;       // pair row (D layout: row=g*4+r)
                    int col  = nt * 16 + l16;
                    int byte = rr * 256 + ((2 * col) ^ ((rr & 7) << 4));
                    *(__bf16*)(hb + byte) = (__bf16)hv;
                }

        // ---- GEMM2: out = h @ W2 + b2 ----
        f32x4 acc2[2][7];
        #pragma unroll
        for (int nt = 0; nt < 7; nt++) {
            f32x4 init = {b2v[nt], b2v[nt], b2v[nt], b2v[nt]};
            acc2[0][nt] = init; acc2[1][nt] = init;
        }
        #pragma unroll
        for (int ks = 0; ks < 4; ks++) {
            bf16x8 ah[2];
            #pragma unroll
            for (int s = 0; s < 2; s++) {
                int row = s * 16 + l16;
                ah[s] = *(const bf16x8*)(hb + row * 256 + ((64 * ks + 16 * g) ^ ((row & 7) << 4)));
            }
            #pragma unroll
            for (int nt = 0; nt < 7; nt++) {
                int row = nt * 16 + l16;
                bf16x8 bf = *(const bf16x8*)(smem + LDS_W2T + row * 256 + ((64 * ks + 16 * g) ^ ((row & 7) << 4)));
                acc2[0][nt] = __builtin_amdgcn_mfma_f32_16x16x32_bf16(ah[0], bf, acc2[0][nt], 0, 0, 0);
                acc2[1][nt] = __builtin_amdgcn_mfma_f32_16x16x32_bf16(ah[1], bf, acc2[1][nt], 0, 0, 0);
            }
        }

        // ---- store: split dist (n<64) / ang (64<=n<100) ----
        const size_t rowbase = (size_t)(bi * NSEQ + i) * NSEQ + j0;
        #pragma unroll
        for (int s = 0; s < 2; s++)
            #pragma unroll
            for (int r = 0; r < 4; r++) {
                size_t prow = rowbase + s * 16 + g * 4 + r;
                float* dptr = dist + prow * 64;
                float* aptr = ang  + prow * 36;
                #pragma unroll
                for (int nt = 0; nt < 7; nt++) {
                    float v = acc2[s][nt][r];
                    int n = nt * 16 + l16;
                    if (n < 64)            dptr[n] = v;
                    else if (n < DHID)     aptr[n - 64] = v;
                }
            }
    }
}

extern "C" void kernel_launch(void* const* d_in, const int* in_sizes, int n_in,
                              void* d_out, int out_size, void* d_ws, size_t ws_size,
                              hipStream_t stream) {
    const float* x  = (const float*)d_in[0];
    const float* Wd = (const float*)d_in[1];
    const float* bd = (const float*)d_in[2];
    const float* W1 = (const float*)d_in[3];
    const float* b1 = (const float*)d_in[4];
    const float* W2 = (const float*)d_in[5];
    const float* b2 = (const float*)d_in[6];

    float* dist = (float*)d_out;                                   // 2*512*512*64
    float* ang  = dist + (size_t)NBATCH * NSEQ * NSEQ * 64;        // 2*512*512*36
    float* qk   = (float*)d_ws;                                    // 1024*128 fp32

    (void)hipFuncSetAttribute(reinterpret_cast<const void*>(&pair_mlp_kernel),
                              hipFuncAttributeMaxDynamicSharedMemorySize, LDS_TOT);

    proj_kernel<<<NBATCH * NSEQ, 128, 0, stream>>>(x, Wd, bd, qk);
    pair_mlp_kernel<<<256, 512, LDS_TOT, stream>>>(qk, W1, b1, W2, b2, dist, ang);
}

// Round 3
// 250.785 us; speedup vs baseline: 1.1133x; 1.1133x over previous
//
#include <hip/hip_runtime.h>
#include <hip/hip_bf16.h>
#include <cstdint>

#define NBATCH 2
#define NSEQ   512
#define DHID   100

typedef __bf16 bf16x8 __attribute__((ext_vector_type(8)));
typedef __bf16 bf16x4 __attribute__((ext_vector_type(4)));
typedef float  f32x4  __attribute__((ext_vector_type(4)));

// ---------------- kernel 1: qk = x @ W_down + b_down (fp32, exact) ----------------
__global__ __launch_bounds__(128)
void proj_kernel(const float* __restrict__ x, const float* __restrict__ Wd,
                 const float* __restrict__ bd, float* __restrict__ qk)
{
    __shared__ float xs[512];
    const int row = blockIdx.x;      // 0..1023  (= b*512 + n)
    const int tid = threadIdx.x;     // 0..127   (= output column)
    const float* xr = x + row * 512;
    #pragma unroll
    for (int e = 0; e < 4; e++) xs[tid + 128 * e] = xr[tid + 128 * e];
    __syncthreads();
    // 4 independent accumulators: break the fma dependency chain (4cyc latency each)
    float a0 = 0.f, a1 = 0.f, a2 = 0.f, a3 = 0.f;
    const float* wp = Wd + tid;
    #pragma unroll 4
    for (int e = 0; e < 512; e += 4) {
        a0 = fmaf(xs[e],     wp[(e)     * 128], a0);
        a1 = fmaf(xs[e + 1], wp[(e + 1) * 128], a1);
        a2 = fmaf(xs[e + 2], wp[(e + 2) * 128], a2);
        a3 = fmaf(xs[e + 3], wp[(e + 3) * 128], a3);
    }
    qk[row * 128 + tid] = bd[tid] + ((a0 + a1) + (a2 + a3));
}

// ---------------- kernel 2: pairwise MLP ----------------
// Swapped-operand MFMA: A = W^T fragment (n rows), B = pw fragment (pair cols).
// D layout: col(lane&15) = pair, row n = nt*16 + g*4 + reg  -> each lane holds 4
// CONSECUTIVE output channels -> dwordx4 global stores, b64 LDS h-writes.
// LDS: W1T swz [112][128]bf16 @0, W2T swz @28672, h per-wave [32][128]bf16 @57344+w*8192.
// Swizzle: byte_in_row ^= (row&7)<<4.

#define LDS_W2T  28672
#define LDS_H    57344
#define LDS_TOT  122880

__global__ __launch_bounds__(512, 2)
void pair_mlp_kernel(const float* __restrict__ qk,
                     const float* __restrict__ W1, const float* __restrict__ b1,
                     const float* __restrict__ W2, const float* __restrict__ b2,
                     float* __restrict__ dist, float* __restrict__ ang)
{
    extern __shared__ char smem[];
    const int tid  = threadIdx.x;
    const int w    = tid >> 6;        // wave 0..7
    const int lane = tid & 63;
    const int l16  = lane & 15;
    const int g    = lane >> 4;       // 0..3
    const int swz  = (l16 & 7) << 4;  // row-XOR swizzle (rows are l16-indexed everywhere)

    // ---- zero all LDS (zero-padding of h k=112..127, W pads) ----
    for (int idx = tid; idx < LDS_TOT / 4; idx += 512)
        ((float*)smem)[idx] = 0.f;
    __syncthreads();

    // ---- stage weights (once per block; bf16, swizzled, transposed) ----
    for (int idx = tid; idx < 100 * 128; idx += 512) {       // W1T[n][k] = W1[k][n]
        int n = idx >> 7, k = idx & 127;
        int byte = n * 256 + ((2 * k) ^ ((n & 7) << 4));
        *(__bf16*)(smem + byte) = (__bf16)W1[k * DHID + n];
    }
    for (int idx = tid; idx < 100 * 100; idx += 512) {       // W2T[n][k] = W2[k][n]
        int n = idx / 100, k = idx % 100;
        int byte = LDS_W2T + n * 256 + ((2 * k) ^ ((n & 7) << 4));
        *(__bf16*)(smem + byte) = (__bf16)W2[k * DHID + n];
    }
    __syncthreads();

    // ---- per-lane bias vectors: n = nt*16 + g*4 + r  ->  f32x4 direct load ----
    f32x4 b1v[7], b2v[7];
    #pragma unroll
    for (int nt = 0; nt < 7; nt++) {
        int n0 = nt * 16 + g * 4;
        if (n0 + 3 < DHID) { b1v[nt] = *(const f32x4*)(b1 + n0); b2v[nt] = *(const f32x4*)(b2 + n0); }
        else               { b1v[nt] = (f32x4){0,0,0,0};         b2v[nt] = (f32x4){0,0,0,0}; }
    }

    char* hb = smem + LDS_H + w * 8192;
    const int TILES = NBATCH * (NSEQ / 8) * (NSEQ / 32);  // 2048

    for (int t = blockIdx.x; t < TILES; t += gridDim.x) {
        int tmp = t;
        const int jb = tmp & 15;  tmp >>= 4;
        const int ib = tmp & 63;  tmp >>= 6;
        const int bi = tmp;
        const int i  = ib * 8 + w;
        const int j0 = jb * 32;

        // ---- q for this wave's i ----
        const float* qrow = qk + (size_t)(bi * NSEQ + i) * 128;
        f32x4 qa0 = *(const f32x4*)(qrow + g * 8);
        f32x4 qa1 = *(const f32x4*)(qrow + g * 8 + 4);
        f32x4 qb0 = *(const f32x4*)(qrow + 32 + g * 8);
        f32x4 qb1 = *(const f32x4*)(qrow + 32 + g * 8 + 4);

        // ---- pw fragments in registers (identical layout for A- and B-operand) ----
        bf16x8 af[2][4];
        #pragma unroll
        for (int s = 0; s < 2; s++) {
            const float* krow = qk + (size_t)(bi * NSEQ + j0 + s * 16 + l16) * 128 + 64;
            f32x4 ka0 = *(const f32x4*)(krow + g * 8);
            f32x4 ka1 = *(const f32x4*)(krow + g * 8 + 4);
            f32x4 kb0 = *(const f32x4*)(krow + 32 + g * 8);
            f32x4 kb1 = *(const f32x4*)(krow + 32 + g * 8 + 4);
            #pragma unroll
            for (int j = 0; j < 4; j++) {
                af[s][0][j]     = (__bf16)(qa0[j] * ka0[j]);
                af[s][0][j + 4] = (__bf16)(qa1[j] * ka1[j]);
                af[s][1][j]     = (__bf16)(qb0[j] * kb0[j]);
                af[s][1][j + 4] = (__bf16)(qb1[j] * kb1[j]);
                af[s][2][j]     = (__bf16)(ka0[j] - qa0[j]);
                af[s][2][j + 4] = (__bf16)(ka1[j] - qa1[j]);
                af[s][3][j]     = (__bf16)(kb0[j] - qb0[j]);
                af[s][3][j + 4] = (__bf16)(kb1[j] - qb1[j]);
            }
        }

        // ---- GEMM1: A = W1T frag, B = pw frag ----
        f32x4 acc1[2][7];
        #pragma unroll
        for (int nt = 0; nt < 7; nt++) { acc1[0][nt] = b1v[nt]; acc1[1][nt] = b1v[nt]; }
        #pragma unroll
        for (int nt = 0; nt < 7; nt++) {
            const int rbase = (nt * 16 + l16) * 256;
            #pragma unroll
            for (int ks = 0; ks < 4; ks++) {
                bf16x8 wf = *(const bf16x8*)(smem + rbase + ((64 * ks + 16 * g) ^ swz));
                acc1[0][nt] = __builtin_amdgcn_mfma_f32_16x16x32_bf16(wf, af[0][ks], acc1[0][nt], 0, 0, 0);
                acc1[1][nt] = __builtin_amdgcn_mfma_f32_16x16x32_bf16(wf, af[1][ks], acc1[1][nt], 0, 0, 0);
            }
        }

        // ---- silu -> packed bf16x4 -> wave-private LDS (b64 writes) ----
        #pragma unroll
        for (int s = 0; s < 2; s++) {
            char* hrow = hb + (s * 16 + l16) * 256;
            #pragma unroll
            for (int nt = 0; nt < 7; nt++) {
                bf16x4 hv;
                #pragma unroll
                for (int r = 0; r < 4; r++) {
                    float z = acc1[s][nt][r];
                    float v = z * __builtin_amdgcn_rcpf(1.f + __expf(-z));
                    if (nt == 6 && g > 0) v = 0.f;       // channels 100..111 exact zero
                    hv[r] = (__bf16)v;
                }
                *(bf16x4*)(hrow + ((nt * 32 + g * 8) ^ swz)) = hv;
            }
        }

        // ---- GEMM2: A = W2T frag, B = h frag ----
        f32x4 acc2[2][7];
        #pragma unroll
        for (int nt = 0; nt < 7; nt++) { acc2[0][nt] = b2v[nt]; acc2[1][nt] = b2v[nt]; }
        #pragma unroll
        for (int ks = 0; ks < 4; ks++) {
            bf16x8 ah[2];
            #pragma unroll
            for (int s = 0; s < 2; s++)
                ah[s] = *(const bf16x8*)(hb + (s * 16 + l16) * 256 + ((ks * 64 + g * 16) ^ swz));
            #pragma unroll
            for (int nt = 0; nt < 7; nt++) {
                bf16x8 wf = *(const bf16x8*)(smem + LDS_W2T + (nt * 16 + l16) * 256 + ((ks * 64 + 16 * g) ^ swz));
                acc2[0][nt] = __builtin_amdgcn_mfma_f32_16x16x32_bf16(wf, ah[0], acc2[0][nt], 0, 0, 0);
                acc2[1][nt] = __builtin_amdgcn_mfma_f32_16x16x32_bf16(wf, ah[1], acc2[1][nt], 0, 0, 0);
            }
        }

        // ---- coalesced dwordx4 stores: lane holds n = nt*16+g*4 .. +3 of pair l16 ----
        const size_t rowbase = (size_t)(bi * NSEQ + i) * NSEQ + j0;
        #pragma unroll
        for (int s = 0; s < 2; s++) {
            size_t prow = rowbase + s * 16 + l16;
            float* dp = dist + prow * 64;
            float* ap = ang  + prow * 36;
            #pragma unroll
            for (int nt = 0; nt < 4; nt++)
                *(f32x4*)(dp + nt * 16 + g * 4) = acc2[s][nt];
            *(f32x4*)(ap + g * 4)      = acc2[s][4];
            *(f32x4*)(ap + 16 + g * 4) = acc2[s][5];
            if (g == 0) *(f32x4*)(ap + 32) = acc2[s][6];   // n=96..99
        }
    }
}

extern "C" void kernel_launch(void* const* d_in, const int* in_sizes, int n_in,
                              void* d_out, int out_size, void* d_ws, size_t ws_size,
                              hipStream_t stream) {
    const float* x  = (const float*)d_in[0];
    const float* Wd = (const float*)d_in[1];
    const float* bd = (const float*)d_in[2];
    const float* W1 = (const float*)d_in[3];
    const float* b1 = (const float*)d_in[4];
    const float* W2 = (const float*)d_in[5];
    const float* b2 = (const float*)d_in[6];

    float* dist = (float*)d_out;                                   // 2*512*512*64
    float* ang  = dist + (size_t)NBATCH * NSEQ * NSEQ * 64;        // 2*512*512*36
    float* qk   = (float*)d_ws;                                    // 1024*128 fp32

    (void)hipFuncSetAttribute(reinterpret_cast<const void*>(&pair_mlp_kernel),
                              hipFuncAttributeMaxDynamicSharedMemorySize, LDS_TOT);

    proj_kernel<<<NBATCH * NSEQ, 128, 0, stream>>>(x, Wd, bd, qk);
    pair_mlp_kernel<<<256, 512, LDS_TOT, stream>>>(qk, W1, b1, W2, b2, dist, ang);
}